// Round 4
// baseline (4037.267 us; speedup 1.0000x reference)
//
#include <hip/hip_runtime.h>
#include <hip/hip_bf16.h>

using bf16 = __hip_bfloat16;

#define CO_BLK 8
#define CCHUNK 8

__device__ __forceinline__ float b2f(bf16 v) { return __bfloat162float(v); }

// Load element i of an EXTERNAL tensor whose dtype is runtime-determined:
// isbf=1 -> bf16, isbf=0 -> f32.
__device__ __forceinline__ float ldin(const void* p, int i, int isbf) {
    return isbf ? b2f(((const bf16*)p)[i]) : ((const float*)p)[i];
}

// ---------------------------------------------------------------------------
// dtype detector: one block reads 256 words of cur_x. If data is bf16-packed
// gaussians, the low 16 bits of each word are a bf16 value whose exponent
// field (bits 14..7) concentrates near 126. If data is f32 gaussians, those
// bits are uniform mantissa bits (~10% in-range). Vote threshold 128/256.
// ---------------------------------------------------------------------------
__global__ void detect_kernel(const unsigned* __restrict__ x, int* __restrict__ flag)
{
    int tid = threadIdx.x;            // 64 threads
    int cnt = 0;
    for (int i = tid; i < 256; i += 64) {
        unsigned e = (x[i] >> 7) & 0xFFu;
        cnt += (e >= 110u && e <= 135u) ? 1 : 0;
    }
#pragma unroll
    for (int off = 32; off > 0; off >>= 1) cnt += __shfl_down(cnt, off, 64);
    if (tid == 0) *flag = (cnt >= 128) ? 1 : 0;
}

// ---------------------------------------------------------------------------
// Generic 3x3 conv, pad=1. Internal activations are f32. EXTIN: input tensor
// is an external (flag-dtype) tensor; otherwise f32 intermediate. Weights,
// bias, beta are always external. smap/dep are f32 intermediates.
// SCALEMAP: input *= smap[b,y,x];  EPI: out = dep + beta*(conv+bias), may
// alias dep (in-place, same-thread read-before-write).
// ---------------------------------------------------------------------------
template<bool SCALEMAP, bool EPI, bool EXTIN>
__global__ __launch_bounds__(256, 2)
void conv3x3_kernel(const void* __restrict__ in, const void* __restrict__ wgt,
                    const void* __restrict__ bias, const float* __restrict__ smap,
                    const float* dep, const void* __restrict__ betap,
                    float* out, const int* __restrict__ flagp,
                    int Cin, int Cout, int H, int W)
{
    __shared__ float s_in[CCHUNK][34][36];
    __shared__ float s_w[CO_BLK][CCHUNK][10];

    const int isbf = *flagp;
    const int tid = threadIdx.x;
    const int tx = tid & 15, ty = tid >> 4;
    const int tilesX = W >> 5;
    const int x0 = (blockIdx.x % tilesX) << 5;
    const int y0 = (blockIdx.x / tilesX) << 5;
    const int b  = blockIdx.y;
    const int co0 = blockIdx.z * CO_BLK;
    const int HW = H * W;

    float acc[CO_BLK][4];
#pragma unroll
    for (int i = 0; i < CO_BLK; i++)
#pragma unroll
        for (int j = 0; j < 4; j++) acc[i][j] = 0.f;

    for (int c0 = 0; c0 < Cin; c0 += CCHUNK) {
        __syncthreads();
        for (int i = tid; i < CCHUNK * 34 * 34; i += 256) {
            int ci = i / (34 * 34);
            int rem = i - ci * (34 * 34);
            int r = rem / 34, c = rem - r * 34;
            int gy = y0 + r - 1, gx = x0 + c - 1;
            float v = 0.f;
            if ((unsigned)gy < (unsigned)H && (unsigned)gx < (unsigned)W) {
                int gidx = (b * Cin + c0 + ci) * HW + gy * W + gx;
                v = EXTIN ? ldin(in, gidx, isbf) : ((const float*)in)[gidx];
                if (SCALEMAP) v *= smap[b * HW + gy * W + gx];
            }
            s_in[ci][r][c] = v;
        }
        for (int i = tid; i < CO_BLK * CCHUNK * 9; i += 256) {
            int co = i / (CCHUNK * 9);
            int rem = i - co * (CCHUNK * 9);
            int ci = rem / 9, k = rem - ci * 9;
            s_w[co][ci][k] = ldin(wgt, ((co0 + co) * Cin + c0 + ci) * 9 + k, isbf);
        }
        __syncthreads();

#pragma unroll 2
        for (int ci = 0; ci < CCHUNK; ci++) {
            float inv[4][4];
#pragma unroll
            for (int r = 0; r < 4; r++)
#pragma unroll
                for (int c = 0; c < 4; c++)
                    inv[r][c] = s_in[ci][2 * ty + r][2 * tx + c];
#pragma unroll
            for (int co = 0; co < CO_BLK; co++) {
                float w9[9];
#pragma unroll
                for (int k = 0; k < 9; k++) w9[k] = s_w[co][ci][k];
#pragma unroll
                for (int py = 0; py < 2; py++)
#pragma unroll
                    for (int px = 0; px < 2; px++) {
                        float a = acc[co][py * 2 + px];
#pragma unroll
                        for (int ky = 0; ky < 3; ky++)
#pragma unroll
                            for (int kx = 0; kx < 3; kx++)
                                a = fmaf(inv[py + ky][px + kx], w9[ky * 3 + kx], a);
                        acc[co][py * 2 + px] = a;
                    }
            }
        }
    }

    const float beta = EPI ? ldin(betap, 0, isbf) : 0.f;
#pragma unroll
    for (int co = 0; co < CO_BLK; co++) {
        float bi = ldin(bias, co0 + co, isbf);
#pragma unroll
        for (int py = 0; py < 2; py++)
#pragma unroll
            for (int px = 0; px < 2; px++) {
                int y = y0 + 2 * ty + py, x = x0 + 2 * tx + px;
                int idx = (b * Cout + co0 + co) * HW + y * W + x;
                float v = acc[co][py * 2 + px] + bi;
                if (EPI) {
                    float d = dep[idx];     // read before write; same thread/idx
                    v = d + beta * v;
                }
                out[idx] = v;
            }
    }
}

// ---------------------------------------------------------------------------
// BN stats over f32 intermediate u: scale/shift per channel, y = x*sc + sh.
// g/be are external (flag-dtype).
// ---------------------------------------------------------------------------
__global__ __launch_bounds__(256)
void bn_stats_kernel(const float* __restrict__ u, const void* __restrict__ g,
                     const void* __restrict__ be, float* __restrict__ ss,
                     const int* __restrict__ flagp, int C, int B, int HW)
{
    int c = blockIdx.x, tid = threadIdx.x;
    float s = 0.f, s2 = 0.f;
    int nvec = HW >> 2;
    for (int b = 0; b < B; b++) {
        const float4* p = (const float4*)(u + (size_t)(b * C + c) * HW);
        for (int i = tid; i < nvec; i += 256) {
            float4 q = p[i];
            s += q.x + q.y + q.z + q.w;
            s2 = fmaf(q.x, q.x, s2);
            s2 = fmaf(q.y, q.y, s2);
            s2 = fmaf(q.z, q.z, s2);
            s2 = fmaf(q.w, q.w, s2);
        }
    }
#pragma unroll
    for (int off = 32; off > 0; off >>= 1) {
        s += __shfl_down(s, off, 64);
        s2 += __shfl_down(s2, off, 64);
    }
    __shared__ float red[4][2];
    int wave = tid >> 6, lane = tid & 63;
    if (lane == 0) { red[wave][0] = s; red[wave][1] = s2; }
    __syncthreads();
    if (tid == 0) {
        float S = red[0][0] + red[1][0] + red[2][0] + red[3][0];
        float S2 = red[0][1] + red[1][1] + red[2][1] + red[3][1];
        float n = (float)(B * HW);
        float m = S / n;
        float var = fmaxf(S2 / n - m * m, 0.f);
        int isbf = *flagp;
        float sc = ldin(g, c, isbf) * rsqrtf(var + 1e-5f);
        ss[2 * c] = sc;
        ss[2 * c + 1] = ldin(be, c, isbf) - m * sc;
    }
}

// ---------------------------------------------------------------------------
// BN apply + ReLU on f32, 4 elems/thread, in-place safe.
// ---------------------------------------------------------------------------
__global__ __launch_bounds__(256)
void bn_apply_kernel(const float* u, const float* __restrict__ ss,
                     float* r, int C, int HW, int total)
{
    int base = (blockIdx.x * 256 + threadIdx.x) << 2;
    if (base >= total) return;
    int c = (base / HW) % C;
    float sc = ss[2 * c], sh = ss[2 * c + 1];
    float4 q = *(const float4*)(u + base);
    q.x = fmaxf(fmaf(q.x, sc, sh), 0.f);
    q.y = fmaxf(fmaf(q.y, sc, sh), 0.f);
    q.z = fmaxf(fmaf(q.z, sc, sh), 0.f);
    q.w = fmaxf(fmaf(q.w, sc, sh), 0.f);
    *(float4*)(r + base) = q;
}

// ---------------------------------------------------------------------------
// pixel_shuffle(2) + BN + ReLU: y_up f32 [16,256,64,64] -> dep f32 [16,64,128,128]
// ---------------------------------------------------------------------------
__global__ __launch_bounds__(256)
void shuffle_bn_relu_kernel(const float* __restrict__ y, const float* __restrict__ ss,
                            float* __restrict__ dep)
{
    int idx = blockIdx.x * 256 + threadIdx.x;   // 8,388,608 pairs
    int xp = idx & 63;
    int t = idx >> 6;
    int yy = t & 127;
    t >>= 7;
    int cp = t & 63;
    int b = t >> 6;
    int ch0 = 4 * cp + 2 * (yy & 1);
    int src = ((b * 256 + ch0) << 12) + ((yy >> 1) << 6) + xp;
    float v0 = y[src];
    float v1 = y[src + 4096];
    float2 o;
    o.x = fmaxf(fmaf(v0, ss[2 * ch0], ss[2 * ch0 + 1]), 0.f);
    o.y = fmaxf(fmaf(v1, ss[2 * ch0 + 2], ss[2 * ch0 + 3]), 0.f);
    *reinterpret_cast<float2*>(dep + ((((b * 64 + cp) << 7) + yy) << 7) + 2 * xp) = o;
}

// ---------------------------------------------------------------------------
// bilinear up2 (align_corners) + sigmoid: in_map (ext) -> imap f32 [16,128,128]
// ---------------------------------------------------------------------------
__global__ __launch_bounds__(256)
void imap_kernel(const void* __restrict__ im, float* __restrict__ imap,
                 const int* __restrict__ flagp)
{
    int isbf = *flagp;
    int idx = blockIdx.x * 256 + threadIdx.x;   // 262144
    int x = idx & 127, y = (idx >> 7) & 127, b = idx >> 14;
    const float s = (float)(63.0 / 127.0);
    float yy = y * s, xx = x * s;
    int y0 = (int)yy, x0 = (int)xx;
    float wy = yy - y0, wx = xx - x0;
    int y1 = min(y0 + 1, 63), x1 = min(x0 + 1, 63);
    int base = b << 12;
    float v00 = ldin(im, base + (y0 << 6) + x0, isbf);
    float v01 = ldin(im, base + (y0 << 6) + x1, isbf);
    float v10 = ldin(im, base + (y1 << 6) + x0, isbf);
    float v11 = ldin(im, base + (y1 << 6) + x1, isbf);
    float r0 = v00 * (1.f - wy) + v10 * wy;
    float r1 = v01 * (1.f - wy) + v11 * wy;
    float v = r0 * (1.f - wx) + r1 * wx;
    imap[idx] = 1.f / (1.f + expf(-v));
}

// ---------------------------------------------------------------------------
// increase = dilate3x3(imap) - imap
// ---------------------------------------------------------------------------
__global__ __launch_bounds__(256)
void increase_kernel(const float* __restrict__ imap, float* __restrict__ inc)
{
    int idx = blockIdx.x * 256 + threadIdx.x;
    int x = idx & 127, y = (idx >> 7) & 127, b = idx >> 14;
    const float* p = imap + (b << 14);
    float mx = -1e30f;
#pragma unroll
    for (int dy = -1; dy <= 1; dy++) {
        int yyv = y + dy;
        if ((unsigned)yyv < 128u) {
#pragma unroll
            for (int dx = -1; dx <= 1; dx++) {
                int xxv = x + dx;
                if ((unsigned)xxv < 128u) mx = fmaxf(mx, p[(yyv << 7) + xxv]);
            }
        }
    }
    inc[idx] = mx - p[(y << 7) + x];
}

// ---------------------------------------------------------------------------
// r3 f32 -> d_out[0 : 16.7M] in output dtype (flag)
// ---------------------------------------------------------------------------
__global__ __launch_bounds__(256)
void write_out_kernel(const float* __restrict__ src, void* __restrict__ dst,
                      const int* __restrict__ flagp, int total)
{
    int isbf = *flagp;
    int base = (blockIdx.x * 256 + threadIdx.x) << 2;
    if (base >= total) return;
    float4 q = *(const float4*)(src + base);
    if (isbf) {
        union { ushort2 u2[2]; uint2 u; } o;
        o.u2[0] = ushort2{(unsigned short)(__bfloat16_as_ushort(__float2bfloat16(q.x))),
                          (unsigned short)(__bfloat16_as_ushort(__float2bfloat16(q.y)))};
        o.u2[1] = ushort2{(unsigned short)(__bfloat16_as_ushort(__float2bfloat16(q.z))),
                          (unsigned short)(__bfloat16_as_ushort(__float2bfloat16(q.w)))};
        *(uint2*)((bf16*)dst + base) = o.u;
    } else {
        *(float4*)((float*)dst + base) = q;
    }
}

// ---------------------------------------------------------------------------
// 7x7 conv, 64 -> 1, pad=3: r3 f32 -> output_map at d_out element 16.7M+
// ---------------------------------------------------------------------------
__global__ __launch_bounds__(256)
void conv7x7_kernel(const float* __restrict__ r, const void* __restrict__ w,
                    const void* __restrict__ bias, void* __restrict__ outv,
                    const int* __restrict__ flagp)
{
    __shared__ float s_in[4][70][22];
    const int isbf = *flagp;
    int tid = threadIdx.x;
    int tx = tid & 15, ty = tid >> 4;
    int x0 = blockIdx.x * 16, y0 = blockIdx.y * 64, b = blockIdx.z;
    float acc[4] = {0.f, 0.f, 0.f, 0.f};

    for (int c0 = 0; c0 < 64; c0 += 4) {
        __syncthreads();
        for (int i = tid; i < 4 * 70 * 22; i += 256) {
            int ci = i / (70 * 22);
            int rem = i - ci * (70 * 22);
            int rr = rem / 22, cc = rem - rr * 22;
            int gy = y0 + rr - 3, gx = x0 + cc - 3;
            float v = 0.f;
            if ((unsigned)gy < 128u && (unsigned)gx < 128u)
                v = r[((b * 64 + c0 + ci) << 14) + (gy << 7) + gx];
            s_in[ci][rr][cc] = v;
        }
        __syncthreads();
        for (int ci = 0; ci < 4; ci++) {
            float wr[49];
#pragma unroll
            for (int k = 0; k < 49; k++) wr[k] = ldin(w, (c0 + ci) * 49 + k, isbf);
#pragma unroll
            for (int rr = 0; rr < 10; rr++) {
                float row[7];
#pragma unroll
                for (int c = 0; c < 7; c++) row[c] = s_in[ci][4 * ty + rr][tx + c];
#pragma unroll
                for (int oy = 0; oy < 4; oy++) {
                    int ky = rr - oy;
                    if (ky >= 0 && ky <= 6) {
#pragma unroll
                        for (int kx = 0; kx < 7; kx++)
                            acc[oy] = fmaf(row[kx], wr[ky * 7 + kx], acc[oy]);
                    }
                }
            }
        }
    }
    float bi = ldin(bias, 0, isbf);
#pragma unroll
    for (int oy = 0; oy < 4; oy++) {
        int y = y0 + 4 * ty + oy;
        int oidx = 16777216 + (b << 14) + (y << 7) + x0 + tx;
        float v = acc[oy] + bi;
        if (isbf) ((bf16*)outv)[oidx] = __float2bfloat16(v);
        else      ((float*)outv)[oidx] = v;
    }
}

// ---------------------------------------------------------------------------
// ws layout (f32 intermediates; ~134.25 MB):
//   [0, 67108864)            W0f  (y_up / u1 / u3 / r3)
//       [0,1MB) imapF, [1MB,2MB) incF   (live steps 4-6 while y_up dead)
//   [67108864, 134217728)    W1f  (dep / t / u2 / r2)
//   [134217728, +2KB)        ss   (BN scale/shift)
//   [134221824, +4B)         flag (dtype: 1=bf16, 0=f32)
// ---------------------------------------------------------------------------
extern "C" void kernel_launch(void* const* d_in, const int* in_sizes, int n_in,
                              void* d_out, int out_size, void* d_ws, size_t ws_size,
                              hipStream_t stream)
{
    (void)in_sizes; (void)n_in; (void)out_size; (void)ws_size;

    const void* cur_x  = d_in[0];
    const void* dep_x  = d_in[1];
    const void* in_map = d_in[2];
    const void* up_w   = d_in[3];
    const void* up_b   = d_in[4];
    const void* up_g   = d_in[5];
    const void* up_be  = d_in[6];
    const void* conv2_w = d_in[7];
    const void* conv2_b = d_in[8];
    const void* beta    = d_in[9];
    const void* d1_w = d_in[10];
    const void* d1_b = d_in[11];
    const void* d1_g = d_in[12];
    const void* d1_be = d_in[13];
    const void* d2_w = d_in[14];
    const void* d2_b = d_in[15];
    const void* d2_g = d_in[16];
    const void* d2_be = d_in[17];
    const void* d3_w = d_in[18];
    const void* d3_b = d_in[19];
    const void* d3_g = d_in[20];
    const void* d3_be = d_in[21];
    const void* out_w = d_in[22];
    const void* out_b = d_in[23];

    char* ws = (char*)d_ws;
    float* W0f   = (float*)(ws);
    float* imapF = (float*)(ws);                    // overlaps W0f[0:1MB]
    float* incF  = (float*)(ws + 1048576);          // overlaps W0f[1MB:2MB]
    float* W1f   = (float*)(ws + 67108864);
    float* ss    = (float*)(ws + 134217728);
    int*   flag  = (int*)(ws + 134221824);

    // 0. dtype detection
    detect_kernel<<<1, 64, 0, stream>>>((const unsigned*)cur_x, flag);
    // 1. y_up = conv3x3(dep_x; up) -> W0f [16,256,64,64]
    conv3x3_kernel<false, false, true><<<dim3(4, 16, 32), 256, 0, stream>>>(
        dep_x, up_w, up_b, nullptr, nullptr, nullptr, W0f, flag, 128, 256, 64, 64);
    // 2. BN stats (256 ch)
    bn_stats_kernel<<<256, 256, 0, stream>>>(W0f, up_g, up_be, ss, flag, 256, 16, 4096);
    // 3. dep = pixel_shuffle(relu(bn(y_up))) -> W1f; y_up dead after
    shuffle_bn_relu_kernel<<<32768, 256, 0, stream>>>(W0f, ss, W1f);
    // 4. imap = sigmoid(up2(in_map)) -> imapF
    imap_kernel<<<1024, 256, 0, stream>>>(in_map, imapF, flag);
    // 5. increase -> incF
    increase_kernel<<<1024, 256, 0, stream>>>(imapF, incF);
    // 6. t = dep + beta*conv3x3(cur_x * inc) -> W1f in place
    conv3x3_kernel<true, true, true><<<dim3(16, 16, 8), 256, 0, stream>>>(
        cur_x, conv2_w, conv2_b, incF, W1f, beta, W1f, flag, 64, 64, 128, 128);
    // 7. u1 = conv(t;d1) -> W0f ; BN ; relu in place
    conv3x3_kernel<false, false, false><<<dim3(16, 16, 8), 256, 0, stream>>>(
        W1f, d1_w, d1_b, nullptr, nullptr, nullptr, W0f, flag, 64, 64, 128, 128);
    bn_stats_kernel<<<64, 256, 0, stream>>>(W0f, d1_g, d1_be, ss, flag, 64, 16, 16384);
    bn_apply_kernel<<<16384, 256, 0, stream>>>(W0f, ss, W0f, 64, 16384, 16777216);
    // 8. u2 = conv(r1;d2) -> W1f ; BN ; relu in place
    conv3x3_kernel<false, false, false><<<dim3(16, 16, 8), 256, 0, stream>>>(
        W0f, d2_w, d2_b, nullptr, nullptr, nullptr, W1f, flag, 64, 64, 128, 128);
    bn_stats_kernel<<<64, 256, 0, stream>>>(W1f, d2_g, d2_be, ss, flag, 64, 16, 16384);
    bn_apply_kernel<<<16384, 256, 0, stream>>>(W1f, ss, W1f, 64, 16384, 16777216);
    // 9. u3 = conv(r2;d3) -> W0f ; BN ; relu in place = r3
    conv3x3_kernel<false, false, false><<<dim3(16, 16, 8), 256, 0, stream>>>(
        W1f, d3_w, d3_b, nullptr, nullptr, nullptr, W0f, flag, 64, 64, 128, 128);
    bn_stats_kernel<<<64, 256, 0, stream>>>(W0f, d3_g, d3_be, ss, flag, 64, 16, 16384);
    bn_apply_kernel<<<16384, 256, 0, stream>>>(W0f, ss, W0f, 64, 16384, 16777216);
    // 10. r3 -> d_out (output dtype per flag)
    write_out_kernel<<<16384, 256, 0, stream>>>(W0f, d_out, flag, 16777216);
    // 11. output_map = conv7x7(r3) -> d_out + 16.7M
    conv7x7_kernel<<<dim3(8, 2, 16), 256, 0, stream>>>(W0f, out_w, out_b, d_out, flag);
}